// Round 2
// baseline (3579.375 us; speedup 1.0000x reference)
//
#include <hip/hip_runtime.h>
#include <cstdint>
#include <cstddef>

typedef __attribute__((ext_vector_type(8))) short short8;   // 8 bf16 (4 VGPRs)
typedef __attribute__((ext_vector_type(2))) float f32x2;
typedef __attribute__((ext_vector_type(4))) float f32x4;

#define HH     100
#define G4     400
#define NCOL   416          // 400 gates + 5 logits + 11 pad = 26 tiles of 16
#define NTIL   26
#define KTN    3            // 3 k-tiles of 32 -> k<96 via MFMA
#define KRES   96           // k=96..99 residual in f32
#define BTOT   8192
#define TST    512
#define GR     16           // rows per phase-group; block owns 2 groups = 32 rows
#define NBLK   256
#define BLOCK  832          // 13 waves; wave w owns tiles 2w, 2w+1
#define ZW     420          // z row stride (words); 420%32=4 -> 2-way banks
#define EPW    404          // Ep2 row stride; 404%32=20 -> ops hit distinct banks
#define TANHC  1.5f
#define EPSF   1e-9f

__device__ unsigned short d_Bhi[NTIL*KTN*64*8];  // [W_h|W_ops|0] hi, B-frag order
__device__ unsigned short d_Blo[NTIL*KTN*64*8];  // lo residual
__device__ float d_Ep2[6*EPW];                   // emb @ W_x   [e][cell][gate], stride EPW
__device__ float d_WresG[NCOL*4];                // rows 96..99 of [W_h|W_ops|0], [n][q]
__device__ float d_Z0[(size_t)BTOT*G4];          // x0 @ W_x    [b][n]

static __device__ __forceinline__ unsigned short bf16hi(float f){
  unsigned u = __float_as_uint(f);
  return (unsigned short)((u + 0x7FFFu + ((u>>16)&1u)) >> 16);   // RNE
}
static __device__ __forceinline__ float bf16f(unsigned short s){
  return __uint_as_float(((unsigned)s)<<16);
}
static __device__ __forceinline__ float frcp(float x){ return __builtin_amdgcn_rcpf(x); }
static __device__ __forceinline__ float sigf(float x){ return frcp(1.0f + __expf(-x)); }
static __device__ __forceinline__ float tanh_f(float x){ return 1.0f - 2.0f*frcp(__expf(2.0f*x) + 1.0f); }

// ---- setup kernels -------------------------------------------------------

// B-frag order for 16x16x32: n = tile*16 + (lane&15), k = kt*32 + (lane>>4)*8 + i
__global__ void setup_bpack(const float* __restrict__ Wh, const float* __restrict__ Wops){
  int idx = blockIdx.x*blockDim.x + threadIdx.x;     // NTIL*KTN*64 = 4992
  if (idx >= NTIL*KTN*64) return;
  int tile = idx/(KTN*64), rem = idx - tile*(KTN*64), kt = rem>>6, ln = rem&63;
  int n = tile*16 + (ln & 15);
  #pragma unroll
  for (int i = 0; i < 8; ++i){
    int k = kt*32 + (ln>>4)*8 + i;                   // k < 96 always
    float w = 0.f;
    if (n < G4)          w = Wh[k*G4 + n];
    else if (n < G4+5)   w = Wops[k*5 + (n - G4)];
    unsigned short hi = bf16hi(w);
    unsigned short lo = bf16hi(w - bf16f(hi));
    d_Bhi[idx*8+i] = hi;
    d_Blo[idx*8+i] = lo;
  }
}

__global__ void setup_misc(const float* __restrict__ emb, const float* __restrict__ Wx,
                           const float* __restrict__ Wh, const float* __restrict__ Wops){
  int idx = blockIdx.x*blockDim.x + threadIdx.x;
  if (idx < 6*EPW){                                  // Ep2 [e][cell][gate], stride EPW
    int e = idx/EPW, r2 = idx - e*EPW, je = r2>>2, g = r2&3;
    float s = 0.f;
    if (je < HH)
      for (int k = 0; k < HH; ++k) s = fmaf(emb[e*HH+k], Wx[k*G4 + g*HH + je], s);
    d_Ep2[idx] = s;
  } else if (idx < 6*EPW + NCOL*4){                  // residual rows 96..99
    int i = idx - 6*EPW, n = i>>2, q = i&3;
    float w = 0.f;
    if (n < G4)        w = Wh[(KRES+q)*G4 + n];
    else if (n < G4+5) w = Wops[(KRES+q)*5 + (n - G4)];
    d_WresG[i] = w;
  }
}

// Z0 = x0 @ W_x, stored [b][n]
__global__ __launch_bounds__(256) void setup_z0(const float* __restrict__ x0,
                                                const float* __restrict__ Wx){
  __shared__ float xs[64*101];
  const int bb = blockIdx.x * 64;                    // 128 blocks
  for (int i = threadIdx.x; i < 64*HH; i += 256){
    int r = i/HH, k = i - r*HH;
    xs[r*101 + k] = x0[(size_t)(bb + r)*HH + k];
  }
  __syncthreads();
  const int bl = threadIdx.x & 63;
  for (int ng = threadIdx.x >> 6; ng < HH; ng += 4){
    f32x4 a = {0.f,0.f,0.f,0.f};
    for (int k = 0; k < HH; ++k){
      f32x4 w = *(const f32x4*)&Wx[k*G4 + ng*4];
      a += w * xs[bl*101 + k];
    }
    *(f32x4*)&d_Z0[(size_t)(bb + bl)*G4 + ng*4] = a;
  }
}

// ---- main persistent kernel ---------------------------------------------
// 256 blocks x 32 rows, 13 waves. Rows split into group A (0..15) and B (16..31)
// running half a step out of phase:
//   P1: G(A) [MFMA+LDS pipe] overlapped with E(B) [VALU/trans pipe]; barrier
//   P2: G(B) overlapped with E(A); barrier
// Same wave issues both workloads each phase, so the two pipes overlap instead
// of serializing across barriers. Register footprint unchanged (B-frags are
// the unified VGPR+AGPR budget -> co-residency of a 2nd block is impossible).

__global__ __launch_bounds__(BLOCK, 4) void rnn_main(
    const float* __restrict__ u, float* __restrict__ out)
{
  __shared__ __align__(16) float zh[2][GR*ZW];                  // 53760 B
  __shared__ __align__(16) unsigned short fhi[2][KTN*64*8];     //  6144 B
  __shared__ __align__(16) unsigned short flo[2][KTN*64*8];     //  6144 B
  __shared__ __align__(16) float h_res[2][GR*4];                //   512 B [r*4+q]
  __shared__ __align__(16) float Ep2_l[6*EPW];                  //  9696 B
  __shared__ __align__(16) float Wres_l[NCOL*4];                //  6656 B
  __shared__ __align__(16) float gn_lds[2][GR*5];               //   640 B
  __shared__ int op_lds[2][GR];                                 //   128 B

  const int tid  = threadIdx.x;
  const int wave = tid >> 6;
  const int lane = tid & 63;
  const int cn   = lane & 15;
  const int q4   = lane >> 4;
  const int row0 = blockIdx.x * (2*GR);
  const int rE   = tid & 15;        // E row within group
  const int c2   = tid >> 4;        // E cell-pair index (tid<800 -> c2<50)
  const int gl   = tid - 704;       // gumbel lanes: wave 11 lanes 0..19

  for (int i = tid; i < 6*EPW;  i += BLOCK) Ep2_l[i]  = d_Ep2[i];
  for (int i = tid; i < NCOL*4; i += BLOCK) Wres_l[i] = d_WresG[i];

  short8 bh[2][KTN], bl[2][KTN];
  {
    const short8* bph = (const short8*)d_Bhi;
    const short8* bpl = (const short8*)d_Blo;
    #pragma unroll
    for (int tl = 0; tl < 2; ++tl)
      #pragma unroll
      for (int kt = 0; kt < KTN; ++kt){
        int fi = ((wave*2 + tl)*KTN + kt)*64 + lane;
        bh[tl][kt] = bph[fi];
        bl[tl][kt] = bpl[fi];
      }
  }

  float cA0=0.f,cA1=0.f,cB0=0.f,cB1=0.f;        // c-state: 2 cells per group
  float lpA=0.f,entA=0.f,lpB=0.f,entB=0.f;

  __syncthreads();

  auto phase = [&](int gG, int t, float& cs0, float& cs1, float& lp, float& ent){
    const int  gE    = gG ^ 1;
    const bool stage = (t == 0);
    const bool doE   = gG ? (t < TST) : (t >= 1);
    const bool addE  = gG ? (t >= 1)  : (t >= 2);
    const bool gnDo  = gG ? (t < TST) : (t >= 1);
    const int  uT    = gG ? t : (t-1);

    // gumbel u prefetch (latency hides under this phase's G+E)
    f32x4 upr;
    if (gnDo && (unsigned)gl < 20u)
      upr = *(const f32x4*)&u[((size_t)uT*BTOT + row0 + gE*GR)*5 + gl*4];

    // ---- E loads (issued early; reads zh[gE] written last phase) ----
    f32x2 zg0, zg1, zg2, zg3;
    f32x4 ea, eb;
    const bool eAct = doE && (tid < 800);
    const int  c0   = c2*2;
    if (eAct){
      const float* zr = &zh[gE][rE*ZW + c0];
      zg0 = *(const f32x2*)&zr[0*HH];
      zg1 = *(const f32x2*)&zr[1*HH];
      zg2 = *(const f32x2*)&zr[2*HH];
      zg3 = *(const f32x2*)&zr[3*HH];
      if (addE){
        int op = op_lds[gE][rE];
        ea = *(const f32x4*)&Ep2_l[op*EPW + c0*4];
        eb = *(const f32x4*)&Ep2_l[op*EPW + c0*4 + 4];
      }
    }

    // ---- G: zh[gG] = h_gG @ [W_h|W_ops] (MFMA k<96 + f32 residual) ----
    if (!stage){
      short8 ah[KTN], al[KTN];
      #pragma unroll
      for (int kt = 0; kt < KTN; ++kt){
        ah[kt] = *(const short8*)&fhi[gG][(kt*64 + lane)*8];
        al[kt] = *(const short8*)&flo[gG][(kt*64 + lane)*8];
      }
      f32x4 hq[4];
      #pragma unroll
      for (int i = 0; i < 4; ++i)                    // broadcast reads [r][q]
        hq[i] = *(const f32x4*)&h_res[gG][(q4*4+i)*4];
      #pragma unroll
      for (int tl = 0; tl < 2; ++tl){
        const int n = (wave*2 + tl)*16 + cn;
        f32x4 acc = {0.f,0.f,0.f,0.f};
        #pragma unroll
        for (int kt = 0; kt < KTN; ++kt){
          acc = __builtin_amdgcn_mfma_f32_16x16x32_bf16(ah[kt], bh[tl][kt], acc, 0,0,0);
          acc = __builtin_amdgcn_mfma_f32_16x16x32_bf16(al[kt], bh[tl][kt], acc, 0,0,0);
          acc = __builtin_amdgcn_mfma_f32_16x16x32_bf16(ah[kt], bl[tl][kt], acc, 0,0,0);
          acc = __builtin_amdgcn_mfma_f32_16x16x32_bf16(al[kt], bl[tl][kt], acc, 0,0,0);
        }
        f32x4 wr = *(const f32x4*)&Wres_l[n*4];
        #pragma unroll
        for (int i = 0; i < 4; ++i)
          acc[i] += hq[i].x*wr.x + hq[i].y*wr.y + hq[i].z*wr.z + hq[i].w*wr.w;
        #pragma unroll
        for (int i = 0; i < 4; ++i)                  // C: row=q4*4+i, col=n
          zh[gG][(q4*4+i)*ZW + n] = acc[i];
      }
      // ---- sampling (wave 12; same-wave LDS dep on its own tile-25 stores) ----
      if (wave == 12 && lane < 16){
        const int r = lane;
        f32x4 l4 = *(const f32x4*)&zh[gG][r*ZW + 400];
        float l5v = zh[gG][r*ZW + 404];
        float l0 = TANHC*tanh_f(l4.x), l1 = TANHC*tanh_f(l4.y);
        float l2 = TANHC*tanh_f(l4.z), l3 = TANHC*tanh_f(l4.w);
        float l4v = TANHC*tanh_f(l5v);
        float lv[5] = {l0,l1,l2,l3,l4v};
        int op = 0; float best = -1e30f, lop = l0;
        #pragma unroll
        for (int o = 0; o < 5; ++o){
          float v = lv[o] + gn_lds[gG][r*5 + o];
          if (v > best){ best = v; op = o; lop = lv[o]; }   // strict >: first-max ties
        }
        float mx = fmaxf(fmaxf(fmaxf(l0,l1), fmaxf(l2,l3)), l4v);
        float se = 0.f;
        #pragma unroll
        for (int o = 0; o < 5; ++o) se += __expf(lv[o] - mx);
        float lse = mx + __logf(se);
        float cur = lse - lop;
        lp  += cur;
        ent += cur * __expf(-cur);
        op_lds[gG][r] = op;
        out[2*BTOT + (size_t)(t-1)*BTOT + row0 + gG*GR + r] = (float)op;
      }
    } else {
      // stage z(0) = x0 @ W_x for this group
      for (int k = tid; k < GR*HH; k += BLOCK){
        int r = k/HH, c4 = k - r*HH;
        *(f32x4*)&zh[gG][r*ZW + c4*4] =
          *(const f32x4*)&d_Z0[(size_t)(row0 + gG*GR + r)*G4 + c4*4];
      }
    }

    // ---- E math: LSTM elementwise, 2 cells/thread ----
    if (eAct){
      if (addE){
        zg0.x += ea.x; zg1.x += ea.y; zg2.x += ea.z; zg3.x += ea.w;
        zg0.y += eb.x; zg1.y += eb.y; zg2.y += eb.z; zg3.y += eb.w;
      }
      float i0 = sigf(zg0.x), f0 = sigf(zg1.x), g0 = tanh_f(zg2.x), o0 = sigf(zg3.x);
      cs0 = f0*cs0 + i0*g0;
      float h0 = o0*tanh_f(cs0);
      float i1 = sigf(zg0.y), f1 = sigf(zg1.y), g1 = tanh_f(zg2.y), o1 = sigf(zg3.y);
      cs1 = f1*cs1 + i1*g1;
      float h1 = o1*tanh_f(cs1);
      if (c2 < 48){                                  // cells <96 -> bf16 hi/lo frags
        unsigned short hh0 = bf16hi(h0), hh1 = bf16hi(h1);
        unsigned short ll0 = bf16hi(h0 - bf16f(hh0));
        unsigned short ll1 = bf16hi(h1 - bf16f(hh1));
        const int kt   = c0 >> 5;
        const int lf   = rE | (((c0 >> 3) & 3) << 4);
        const int base = (kt*64 + lf)*8 + (c0 & 7);  // halfword index, even
        *(unsigned*)&fhi[gE][base] = (unsigned)hh0 | ((unsigned)hh1 << 16);
        *(unsigned*)&flo[gE][base] = (unsigned)ll0 | ((unsigned)ll1 << 16);
      } else {                                       // cells 96..99 -> f32 residual
        *(f32x2*)&h_res[gE][rE*4 + (c2-48)*2] = f32x2{h0, h1};
      }
    }
    // ---- gumbel noise for group gE ----
    if (gnDo && (unsigned)gl < 20u){
      f32x4 gv;
      #pragma unroll
      for (int j = 0; j < 4; ++j)
        gv[j] = -__logf(-__logf(upr[j] + EPSF) + EPSF);
      *(f32x4*)&gn_lds[gE][gl*4] = gv;
    }
  };

  for (int t = 0; t <= TST; ++t){
    phase(0, t, cB0, cB1, lpA, entA);   // P1: G(A)+sample(A) || E(B)
    __syncthreads();
    phase(1, t, cA0, cA1, lpB, entB);   // P2: G(B)+sample(B) || E(A)
    if (t == TST) break;
    __syncthreads();
  }

  if (wave == 12 && lane < 16){
    out[row0 + lane]             = lpA;
    out[row0 + GR + lane]        = lpB;
    out[BTOT + row0 + lane]      = entA;
    out[BTOT + row0 + GR + lane] = entB;
  }
}

extern "C" void kernel_launch(void* const* d_in, const int* in_sizes, int n_in,
                              void* d_out, int out_size, void* d_ws, size_t ws_size,
                              hipStream_t stream) {
  const float* x0   = (const float*)d_in[0];
  const float* Wx   = (const float*)d_in[1];
  const float* Wh   = (const float*)d_in[2];
  const float* Wops = (const float*)d_in[3];
  const float* emb  = (const float*)d_in[4];
  const float* u    = (const float*)d_in[5];
  (void)d_ws; (void)ws_size; (void)in_sizes; (void)n_in;

  setup_bpack<<<(NTIL*KTN*64 + 255)/256, 256, 0, stream>>>(Wh, Wops);
  setup_misc<<<(6*EPW + NCOL*4 + 255)/256, 256, 0, stream>>>(emb, Wx, Wh, Wops);
  setup_z0<<<BTOT/64, 256, 0, stream>>>(x0, Wx);
  rnn_main<<<NBLK, BLOCK, 0, stream>>>(u, (float*)d_out);
}